// Round 1
// baseline (819.394 us; speedup 1.0000x reference)
//
#include <hip/hip_runtime.h>

typedef unsigned short u16;
typedef __attribute__((ext_vector_type(4))) unsigned short u16x4;
typedef __attribute__((ext_vector_type(8))) unsigned short u16x8;
typedef __attribute__((ext_vector_type(4))) float f32x4;
typedef __attribute__((ext_vector_type(8))) __bf16 bf16x8;

__device__ __forceinline__ u16 f2bf(float f) {
  union { float f; unsigned int u; } v; v.f = f;
  unsigned int u = v.u;
  unsigned int r = (u + 0x7fffu + ((u >> 16) & 1u)) >> 16;
  return (u16)r;
}
__device__ __forceinline__ float bf2f(u16 h) {
  union { unsigned int u; float f; } v; v.u = ((unsigned int)h) << 16;
  return v.f;
}
__device__ __forceinline__ f32x4 mfma16(u16x8 a, u16x8 b, f32x4 c) {
  return __builtin_amdgcn_mfma_f32_16x16x32_bf16(
      __builtin_bit_cast(bf16x8, a), __builtin_bit_cast(bf16x8, b), c, 0, 0, 0);
}

// ---------------- fp32 -> bf16 conversion ----------------
__global__ __launch_bounds__(256) void cvt_bf16(const float* __restrict__ x,
                                                u16* __restrict__ y, int n4) {
  int i = blockIdx.x * 256 + threadIdx.x;
  if (i >= n4) return;
  float4 v = ((const float4*)x)[i];
  u16x4 o;
  o.x = f2bf(v.x); o.y = f2bf(v.y); o.z = f2bf(v.z); o.w = f2bf(v.w);
  ((u16x4*)y)[i] = o;
}

// ---------------- GEMM: C[M,1536] = A[M,1536] @ W[1536,1536]^T + bias ----------------
// A, W bf16; C bf16 or fp32. NT layout (both K-contiguous).
template <bool OUT_F32>
__global__ __launch_bounds__(256, 2) void gemm_bf16_nt(
    const u16* __restrict__ A, const u16* __restrict__ W,
    const float* __restrict__ bias, void* __restrict__ Cp, int M) {
  const int K = 1536, N = 1536;
  __shared__ __align__(16) u16 As[128][40];  // +8 pad: stride 80B kills conflicts
  __shared__ __align__(16) u16 Bs[128][40];
  const int tid = threadIdx.x;
  const int lane = tid & 63, wid = tid >> 6;
  const int quad = lane >> 4, l15 = lane & 15;
  const int m0 = blockIdx.y * 128, n0 = blockIdx.x * 128;
  const int wm = (wid >> 1) * 64, wn = (wid & 1) * 64;
  f32x4 acc[4][4];
#pragma unroll
  for (int i = 0; i < 4; ++i)
#pragma unroll
    for (int j = 0; j < 4; ++j)
#pragma unroll
      for (int r = 0; r < 4; ++r) acc[i][j][r] = 0.f;

  for (int k0 = 0; k0 < K; k0 += 32) {
#pragma unroll
    for (int i = 0; i < 2; ++i) {
      int p = tid + i * 256;
      int r = p >> 2, c = (p & 3) * 8;
      int gr = m0 + r;
      u16x8 va;
      if (gr < M) {
        va = *(const u16x8*)(A + (size_t)gr * K + k0 + c);
      } else {
#pragma unroll
        for (int e = 0; e < 8; ++e) va[e] = 0;
      }
      *(u16x8*)&As[r][c] = va;
      *(u16x8*)&Bs[r][c] = *(const u16x8*)(W + (size_t)(n0 + r) * K + k0 + c);
    }
    __syncthreads();
    u16x8 af[4], bfr[4];
#pragma unroll
    for (int i = 0; i < 4; ++i)
      af[i] = *(const u16x8*)&As[wm + i * 16 + l15][quad * 8];
#pragma unroll
    for (int j = 0; j < 4; ++j)
      bfr[j] = *(const u16x8*)&Bs[wn + j * 16 + l15][quad * 8];
#pragma unroll
    for (int i = 0; i < 4; ++i)
#pragma unroll
      for (int j = 0; j < 4; ++j) acc[i][j] = mfma16(af[i], bfr[j], acc[i][j]);
    __syncthreads();
  }
  // epilogue: C/D layout col=lane&15, row=quad*4+reg
#pragma unroll
  for (int i = 0; i < 4; ++i) {
    int row = m0 + wm + i * 16 + quad * 4;
#pragma unroll
    for (int j = 0; j < 4; ++j) {
      int col = n0 + wn + j * 16 + l15;
      float bc = bias[col];
#pragma unroll
      for (int r = 0; r < 4; ++r) {
        if (row + r < M) {
          float v = acc[i][j][r] + bc;
          if (OUT_F32)
            ((float*)Cp)[(size_t)(row + r) * N + col] = v;
          else
            ((u16*)Cp)[(size_t)(row + r) * N + col] = f2bf(v);
        }
      }
    }
  }
}

// ---------------- fused RMSNorm + interleaved RoPE, in-place bf16 ----------------
// oscale folds softmax scale * log2(e) into q (1.0 for k).
__global__ __launch_bounds__(256) void norm_rope(u16* __restrict__ X,
                                                 const float* __restrict__ g,
                                                 const float* __restrict__ fc,
                                                 const float* __restrict__ fs,
                                                 float oscale) {
  const int DIMc = 1536;
  int row = blockIdx.x;
  int tid = threadIdx.x;
  u16* xr = X + (size_t)row * DIMc;
  float xe[3], xo[3];
  float ss = 0.f;
#pragma unroll
  for (int i = 0; i < 3; ++i) {
    int p = tid + i * 256;  // pair index 0..767
    float a = bf2f(xr[2 * p]);
    float b = bf2f(xr[2 * p + 1]);
    xe[i] = a; xo[i] = b;
    ss += a * a + b * b;
  }
#pragma unroll
  for (int m = 1; m < 64; m <<= 1) ss += __shfl_xor(ss, m);
  __shared__ float wss[4];
  __shared__ float rs_sh;
  if ((tid & 63) == 0) wss[tid >> 6] = ss;
  __syncthreads();
  if (tid == 0)
    rs_sh = rsqrtf((wss[0] + wss[1] + wss[2] + wss[3]) * (1.f / 1536.f) + 1e-5f);
  __syncthreads();
  float rs = rs_sh;
#pragma unroll
  for (int i = 0; i < 3; ++i) {
    int p = tid + i * 256;
    int col = 2 * p;
    int dh = col & 127;  // within-head (even) position
    float c = fc[(size_t)row * 128 + dh];
    float s = fs[(size_t)row * 128 + dh + 1];
    float a = xe[i] * rs * g[col];
    float b = xo[i] * rs * g[col + 1];
    xr[col] = f2bf((a * c - b * s) * oscale);
    xr[col + 1] = f2bf((a * s + b * c) * oscale);
  }
}

// ---------------- block-sparse flash attention ----------------
// grid (25 m-tiles, 24 = h*2+t). 64 q-rows/block, 64-key chunks.
__global__ __launch_bounds__(256, 2) void attn_kernel(
    const u16* __restrict__ Q, const u16* __restrict__ Kb,
    const u16* __restrict__ Vb, const int* __restrict__ sel,
    u16* __restrict__ O) {
  const int DIMc = 1536, DHc = 128, HWc = 1560;
  __shared__ __align__(16) u16 Ks[64][136];   // [key][dim], pad 8
  __shared__ __align__(16) u16 Vt[128][72];   // [dim][key], pad 8
  __shared__ __align__(16) u16 Ps[4][64][20]; // per-wave [key][m], pad 4
  const int tid = threadIdx.x;
  const int lane = tid & 63, wid = tid >> 6;
  const int quad = lane >> 4, l15 = lane & 15;
  const int mt = blockIdx.x;
  const int h = blockIdx.y >> 1, t = blockIdx.y & 1;
  int s0 = sel[2 * t];
  const int b0 = s0 > 0 ? s0 : 0;
  const int b1 = sel[2 * t + 1];
  const int nk = (b1 >= 0) ? 2 * HWc : HWc;
  const int m0 = mt * 64;

  // Q A-frags (q pre-scaled by 1/sqrt(128)*log2e): wave's 16 rows indexed by lane&15
  int qrl = m0 + wid * 16 + l15;
  if (qrl > HWc - 1) qrl = HWc - 1;
  const size_t qbase = (size_t)(t * HWc + qrl) * DIMc + h * DHc;
  u16x8 qf[4];
#pragma unroll
  for (int ks = 0; ks < 4; ++ks)
    qf[ks] = *(const u16x8*)(Q + qbase + ks * 32 + quad * 8);

  f32x4 oacc[8];
#pragma unroll
  for (int n = 0; n < 8; ++n)
#pragma unroll
    for (int r = 0; r < 4; ++r) oacc[n][r] = 0.f;
  float mrow[4] = {-1e30f, -1e30f, -1e30f, -1e30f};
  float lrow[4] = {0.f, 0.f, 0.f, 0.f};

  const int skey = tid >> 2, sdb = (tid & 3) * 32;

  for (int kc = 0; kc < nk; kc += 64) {
    // ---- stage K (row-major) and V (transposed) ----
    int kidx = kc + skey;
    if (kidx < nk) {
      int inb1 = (kidx >= HWc);
      int blk = inb1 ? b1 : b0;
      int tok = blk * HWc + kidx - (inb1 ? HWc : 0);
      const u16* kp = Kb + (size_t)tok * DIMc + h * DHc + sdb;
      const u16* vp = Vb + (size_t)tok * DIMc + h * DHc + sdb;
#pragma unroll
      for (int e = 0; e < 4; ++e) {
        u16x8 kv = *(const u16x8*)(kp + e * 8);
        u16x8 vv = *(const u16x8*)(vp + e * 8);
        *(u16x8*)&Ks[skey][sdb + e * 8] = kv;
#pragma unroll
        for (int q2 = 0; q2 < 8; ++q2) Vt[sdb + e * 8 + q2][skey] = vv[q2];
      }
    } else {
      u16x8 z;
#pragma unroll
      for (int e = 0; e < 8; ++e) z[e] = 0;
#pragma unroll
      for (int e = 0; e < 4; ++e) {
        *(u16x8*)&Ks[skey][sdb + e * 8] = z;
#pragma unroll
        for (int q2 = 0; q2 < 8; ++q2) Vt[sdb + e * 8 + q2][skey] = 0;
      }
    }
    __syncthreads();

    // ---- S = Q K^T (scores already in log2 units) ----
    f32x4 s[4];
#pragma unroll
    for (int j = 0; j < 4; ++j)
#pragma unroll
      for (int r = 0; r < 4; ++r) s[j][r] = 0.f;
#pragma unroll
    for (int ks = 0; ks < 4; ++ks) {
#pragma unroll
      for (int j = 0; j < 4; ++j) {
        u16x8 bk = *(const u16x8*)&Ks[j * 16 + l15][ks * 32 + quad * 8];
        s[j] = mfma16(qf[ks], bk, s[j]);
      }
    }
    // mask invalid key columns
#pragma unroll
    for (int j = 0; j < 4; ++j) {
      if (kc + j * 16 + l15 >= nk) {
#pragma unroll
        for (int r = 0; r < 4; ++r) s[j][r] = -1e30f;
      }
    }
    // ---- online softmax (rows = quad*4+reg; reduce over 16 lanes of quad group) ----
    float alpha[4];
#pragma unroll
    for (int r = 0; r < 4; ++r) {
      float v = fmaxf(fmaxf(s[0][r], s[1][r]), fmaxf(s[2][r], s[3][r]));
#pragma unroll
      for (int msk = 1; msk < 16; msk <<= 1) v = fmaxf(v, __shfl_xor(v, msk));
      float mn = fmaxf(mrow[r], v);
      alpha[r] = exp2f(mrow[r] - mn);
      mrow[r] = mn;
    }
    float rsum[4] = {0.f, 0.f, 0.f, 0.f};
#pragma unroll
    for (int j = 0; j < 4; ++j) {
      u16x4 pw;
#pragma unroll
      for (int r = 0; r < 4; ++r) {
        float p = exp2f(s[j][r] - mrow[r]);
        rsum[r] += p;
        pw[r] = f2bf(p);
      }
      // P^T store: [key = j*16+l15][m = quad*4 .. +3] as one b64
      *(u16x4*)&Ps[wid][j * 16 + l15][quad * 4] = pw;
    }
#pragma unroll
    for (int r = 0; r < 4; ++r) {
      float v = rsum[r];
#pragma unroll
      for (int msk = 1; msk < 16; msk <<= 1) v += __shfl_xor(v, msk);
      lrow[r] = lrow[r] * alpha[r] + v;
    }
#pragma unroll
    for (int n = 0; n < 8; ++n)
#pragma unroll
      for (int r = 0; r < 4; ++r) oacc[n][r] *= alpha[r];
    __syncthreads();

    // ---- O += P V ----
#pragma unroll
    for (int ks2 = 0; ks2 < 2; ++ks2) {
      u16x8 pf;
#pragma unroll
      for (int jj = 0; jj < 8; ++jj)
        pf[jj] = Ps[wid][ks2 * 32 + quad * 8 + jj][l15];
#pragma unroll
      for (int n = 0; n < 8; ++n) {
        u16x8 bv = *(const u16x8*)&Vt[n * 16 + l15][ks2 * 32 + quad * 8];
        oacc[n] = mfma16(pf, bv, oacc[n]);
      }
    }
    __syncthreads();
  }

  // ---- epilogue: O /= l, store bf16 ----
#pragma unroll
  for (int r = 0; r < 4; ++r) {
    int rl = m0 + wid * 16 + quad * 4 + r;
    if (rl < HWc) {
      float inv = 1.f / lrow[r];
      size_t base = (size_t)(t * HWc + rl) * DIMc + h * DHc;
#pragma unroll
      for (int n = 0; n < 8; ++n) O[base + n * 16 + l15] = f2bf(oacc[n][r] * inv);
    }
  }
}

extern "C" void kernel_launch(void* const* d_in, const int* in_sizes, int n_in,
                              void* d_out, int out_size, void* d_ws, size_t ws_size,
                              hipStream_t stream) {
  const float* hs  = (const float*)d_in[0];
  const float* his = (const float*)d_in[1];
  const float* fc  = (const float*)d_in[2];
  const float* fs  = (const float*)d_in[3];
  const float* fch = (const float*)d_in[4];
  const float* fsh = (const float*)d_in[5];
  const int*   sel = (const int*)d_in[6];
  const float* Wq  = (const float*)d_in[7];
  const float* bq  = (const float*)d_in[8];
  const float* Wk  = (const float*)d_in[9];
  const float* bk  = (const float*)d_in[10];
  const float* Wv  = (const float*)d_in[11];
  const float* bv  = (const float*)d_in[12];
  const float* Wo  = (const float*)d_in[13];
  const float* bo  = (const float*)d_in[14];
  const float* gq  = (const float*)d_in[15];
  const float* gk  = (const float*)d_in[16];

  const int QT = 3120, KT = 12480, DIMc = 1536;
  u16* p = (u16*)d_ws;
  u16* hsb = p; p += (size_t)QT * DIMc;
  u16* hib = p; p += (size_t)KT * DIMc;
  u16* wqb = p; p += (size_t)DIMc * DIMc;
  u16* wkb = p; p += (size_t)DIMc * DIMc;
  u16* wvb = p; p += (size_t)DIMc * DIMc;
  u16* wob = p; p += (size_t)DIMc * DIMc;
  u16* qb  = p; p += (size_t)QT * DIMc;
  u16* kb2 = p; p += (size_t)KT * DIMc;
  u16* vb2 = p; p += (size_t)KT * DIMc;
  u16* ab  = p; p += (size_t)QT * DIMc;

  auto cvt = [&](const float* src, u16* dst, size_t n) {
    int n4 = (int)(n / 4);
    cvt_bf16<<<dim3((n4 + 255) / 256), dim3(256), 0, stream>>>(src, dst, n4);
  };
  cvt(hs, hsb, (size_t)QT * DIMc);
  cvt(his, hib, (size_t)KT * DIMc);
  cvt(Wq, wqb, (size_t)DIMc * DIMc);
  cvt(Wk, wkb, (size_t)DIMc * DIMc);
  cvt(Wv, wvb, (size_t)DIMc * DIMc);
  cvt(Wo, wob, (size_t)DIMc * DIMc);

  gemm_bf16_nt<false><<<dim3(12, 25), 256, 0, stream>>>(hsb, wqb, bq, qb, QT);
  gemm_bf16_nt<false><<<dim3(12, 98), 256, 0, stream>>>(hib, wkb, bk, kb2, KT);
  gemm_bf16_nt<false><<<dim3(12, 98), 256, 0, stream>>>(hib, wvb, bv, vb2, KT);

  // q gets softmax scale * log2(e) folded in; attention uses exp2
  const float qscale = (float)(0.08838834764831845 * 1.4426950408889634);
  norm_rope<<<dim3(QT), 256, 0, stream>>>(qb, gq, fc, fs, qscale);
  norm_rope<<<dim3(KT), 256, 0, stream>>>(kb2, gk, fch, fsh, 1.0f);

  attn_kernel<<<dim3(25, 24), 256, 0, stream>>>(qb, kb2, vb2, sel, ab);

  gemm_bf16_nt<true><<<dim3(12, 25), 256, 0, stream>>>(ab, wob, bo, d_out, QT);
}

// Round 2
// 683.208 us; speedup vs baseline: 1.1993x; 1.1993x over previous
//
#include <hip/hip_runtime.h>

typedef unsigned short u16;
typedef __attribute__((ext_vector_type(4))) unsigned short u16x4;
typedef __attribute__((ext_vector_type(8))) unsigned short u16x8;
typedef __attribute__((ext_vector_type(4))) float f32x4;
typedef __attribute__((ext_vector_type(8))) __bf16 bf16x8;

__device__ __forceinline__ u16 f2bf(float f) {
  union { float f; unsigned int u; } v; v.f = f;
  unsigned int u = v.u;
  unsigned int r = (u + 0x7fffu + ((u >> 16) & 1u)) >> 16;
  return (u16)r;
}
__device__ __forceinline__ float bf2f(u16 h) {
  union { unsigned int u; float f; } v; v.u = ((unsigned int)h) << 16;
  return v.f;
}
__device__ __forceinline__ f32x4 mfma16(u16x8 a, u16x8 b, f32x4 c) {
  return __builtin_amdgcn_mfma_f32_16x16x32_bf16(
      __builtin_bit_cast(bf16x8, a), __builtin_bit_cast(bf16x8, b), c, 0, 0, 0);
}
// async global->LDS, 16B per lane; LDS dest = wave-uniform base + lane*16
__device__ __forceinline__ void glds16(const void* g, void* l) {
  __builtin_amdgcn_global_load_lds((const __attribute__((address_space(1))) void*)g,
                                   (__attribute__((address_space(3))) void*)l, 16, 0, 0);
}

// ---------------- fp32 -> bf16 conversion ----------------
__global__ __launch_bounds__(256) void cvt_bf16(const float* __restrict__ x,
                                                u16* __restrict__ y, int n4) {
  int i = blockIdx.x * 256 + threadIdx.x;
  if (i >= n4) return;
  float4 v = ((const float4*)x)[i];
  u16x4 o;
  o.x = f2bf(v.x); o.y = f2bf(v.y); o.z = f2bf(v.z); o.w = f2bf(v.w);
  ((u16x4*)y)[i] = o;
}
// 4 weight matrices in one launch (blockIdx.y selects)
__global__ __launch_bounds__(256) void cvt_w4(const float* __restrict__ a, const float* __restrict__ b,
                                              const float* __restrict__ c, const float* __restrict__ d,
                                              u16* __restrict__ oa, u16* __restrict__ ob,
                                              u16* __restrict__ oc, u16* __restrict__ od) {
  int w = blockIdx.y;
  const float* s = w == 0 ? a : w == 1 ? b : w == 2 ? c : d;
  u16* o = w == 0 ? oa : w == 1 ? ob : w == 2 ? oc : od;
  int i = blockIdx.x * 256 + threadIdx.x;  // n4 = 1536*1536/4 = 589824, grid.x=2304
  float4 v = ((const float4*)s)[i];
  u16x4 r;
  r.x = f2bf(v.x); r.y = f2bf(v.y); r.z = f2bf(v.z); r.w = f2bf(v.w);
  ((u16x4*)o)[i] = r;
}

// ---------------- GEMM: C[M,1536] = A[M,1536] @ W[1536,1536]^T + bias ----------------
// BK=64, global_load_lds staging, XOR chunk swizzle (chunk ^= row&7).
// OUT: 0 = bf16 row-major, 1 = f32 row-major, 2 = bf16 transposed (C^T[N][ldt])
template <int OUT>
__global__ __launch_bounds__(256, 2) void gemm_v2(
    const u16* __restrict__ A, const u16* __restrict__ W,
    const float* __restrict__ bias, void* __restrict__ Cp, int M, int ldt) {
  const int K = 1536, N = 1536;
  __shared__ __align__(16) u16 gsm[17408];  // As[128][64] | Bs[128][64]; epi reuses as Ct[128][136]
  u16* As = gsm;
  u16* Bs = gsm + 8192;
  const int tid = threadIdx.x;
  const int lane = tid & 63, wid = tid >> 6;
  const int quad = lane >> 4, l15 = lane & 15;
  const int m0 = blockIdx.y * 128, n0 = blockIdx.x * 128;
  const int wm = (wid >> 1) * 64, wn = (wid & 1) * 64;
  f32x4 acc[4][4];
#pragma unroll
  for (int i = 0; i < 4; ++i)
#pragma unroll
    for (int j = 0; j < 4; ++j)
#pragma unroll
      for (int r = 0; r < 4; ++r) acc[i][j][r] = 0.f;

  const int r8 = lane >> 3, c8 = lane & 7;
  const int gch = c8 ^ r8;  // swizzled global 16B-chunk for this lane

  for (int k0 = 0; k0 < K; k0 += 64) {
#pragma unroll
    for (int inst = 0; inst < 4; ++inst) {
      int row = wid * 32 + inst * 8 + r8;
      glds16(A + ((size_t)(m0 + row) * K + k0 + gch * 8), As + (wid * 32 + inst * 8) * 64);
      glds16(W + ((size_t)(n0 + row) * K + k0 + gch * 8), Bs + (wid * 32 + inst * 8) * 64);
    }
    asm volatile("s_waitcnt vmcnt(0)" ::: "memory");
    __syncthreads();
#pragma unroll
    for (int ks = 0; ks < 2; ++ks) {
      u16x8 af[4], bfr[4];
#pragma unroll
      for (int i = 0; i < 4; ++i) {
        int row = wm + i * 16 + l15;
        af[i] = *(const u16x8*)&As[row * 64 + (((ks * 4 + quad) ^ (l15 & 7)) * 8)];
      }
#pragma unroll
      for (int j = 0; j < 4; ++j) {
        int row = wn + j * 16 + l15;
        bfr[j] = *(const u16x8*)&Bs[row * 64 + (((ks * 4 + quad) ^ (l15 & 7)) * 8)];
      }
#pragma unroll
      for (int i = 0; i < 4; ++i)
#pragma unroll
        for (int j = 0; j < 4; ++j) acc[i][j] = mfma16(af[i], bfr[j], acc[i][j]);
    }
    __syncthreads();
  }

  if (OUT != 2) {
#pragma unroll
    for (int i = 0; i < 4; ++i) {
      int row = m0 + wm + i * 16 + quad * 4;
#pragma unroll
      for (int j = 0; j < 4; ++j) {
        int col = n0 + wn + j * 16 + l15;
        float bc = bias[col];
#pragma unroll
        for (int r = 0; r < 4; ++r) {
          if (row + r < M) {
            float v = acc[i][j][r] + bc;
            if (OUT == 1)
              ((float*)Cp)[(size_t)(row + r) * N + col] = v;
            else
              ((u16*)Cp)[(size_t)(row + r) * N + col] = f2bf(v);
          }
        }
      }
    }
  } else {
    // transposed epilogue: stage C^T tile via LDS, write coalesced along m
    u16* Ct = gsm;  // [128 n][136]
#pragma unroll
    for (int i = 0; i < 4; ++i)
#pragma unroll
      for (int j = 0; j < 4; ++j) {
        int nloc = wn + j * 16 + l15;
        float bc = bias[n0 + nloc];
#pragma unroll
        for (int r = 0; r < 4; ++r) {
          int mloc = wm + i * 16 + quad * 4 + r;
          Ct[nloc * 136 + mloc] = f2bf(acc[i][j][r] + bc);
        }
      }
    __syncthreads();
    int n = tid >> 1, half = tid & 1;
#pragma unroll
    for (int e = 0; e < 8; ++e) {
      int mloc = half * 64 + e * 8;
      if (m0 + mloc < M) {
        u16x8 v = *(const u16x8*)&Ct[n * 136 + mloc];
        *(u16x8*)((u16*)Cp + (size_t)(n0 + n) * ldt + m0 + mloc) = v;
      }
    }
  }
}

// ---------------- fused RMSNorm + interleaved RoPE, in-place bf16 ----------------
__global__ __launch_bounds__(192) void norm_rope2(u16* __restrict__ X,
                                                  const float* __restrict__ g,
                                                  const float* __restrict__ fc,
                                                  const float* __restrict__ fs,
                                                  float oscale) {
  const int DIMc = 1536;
  int row = blockIdx.x;
  int tid = threadIdx.x;
  u16* xr = X + (size_t)row * DIMc + tid * 8;
  u16x8 v = *(const u16x8*)xr;
  float x[8];
  float ss = 0.f;
#pragma unroll
  for (int e = 0; e < 8; ++e) { x[e] = bf2f(v[e]); ss += x[e] * x[e]; }
#pragma unroll
  for (int m = 1; m < 64; m <<= 1) ss += __shfl_xor(ss, m);
  __shared__ float w3[3];
  if ((tid & 63) == 0) w3[tid >> 6] = ss;
  __syncthreads();
  float rs = rsqrtf((w3[0] + w3[1] + w3[2]) * (1.f / 1536.f) + 1e-5f);
  int dhb = (tid * 8) & 127;
  const float* fcr = fc + (size_t)row * 128 + dhb;
  const float* fsr = fs + (size_t)row * 128 + dhb;
  float4 c0 = *(const float4*)fcr, c1 = *(const float4*)(fcr + 4);
  float4 s0 = *(const float4*)fsr, s1 = *(const float4*)(fsr + 4);
  const float* gp = g + tid * 8;
  float4 g0 = *(const float4*)gp, g1 = *(const float4*)(gp + 4);
  float cosv[4] = {c0.x, c0.z, c1.x, c1.z};
  float sinv[4] = {s0.y, s0.w, s1.y, s1.w};
  float gv[8] = {g0.x, g0.y, g0.z, g0.w, g1.x, g1.y, g1.z, g1.w};
  u16x8 o;
#pragma unroll
  for (int p = 0; p < 4; ++p) {
    float a = x[2 * p] * rs * gv[2 * p];
    float b = x[2 * p + 1] * rs * gv[2 * p + 1];
    o[2 * p] = f2bf((a * cosv[p] - b * sinv[p]) * oscale);
    o[2 * p + 1] = f2bf((a * sinv[p] + b * cosv[p]) * oscale);
  }
  *(u16x8*)xr = o;
}

// ---------------- block-sparse attention, S^T formulation, one-pass softmax ----------------
// grid (25 q-tiles of 64, 24 = h*2+t). 256 thr. Chunk = 64 keys.
// Wave w: QK^T for keys w*16..+16 (all 64 q); PV for d rows w*32..+32 (all 64 q).
__global__ __launch_bounds__(256, 3) void attn2(
    const u16* __restrict__ Q, const u16* __restrict__ Kb,
    const u16* __restrict__ VT, const int* __restrict__ sel,
    u16* __restrict__ O) {
  const int HWc = 1560, DIMc = 1536, KT = 12480;
  __shared__ __align__(16) u16 smem[8192 + 8192 + 4352];
  __shared__ float Ls[4][64];
  u16* Ks = smem;          // [64 key][128], 16B-chunk swizzled by key&15
  u16* Vt = smem + 8192;   // [128 d][64], 16B-chunk swizzled by d&7
  u16* Ps = smem + 16384;  // [64 q][68]
  const int tid = threadIdx.x;
  const int lane = tid & 63, wid = tid >> 6;
  const int quad = lane >> 4, l15 = lane & 15;
  const int m0 = blockIdx.x * 64;
  const int h = blockIdx.y >> 1, t = blockIdx.y & 1;
  int s0 = sel[2 * t];
  const int b0 = s0 > 0 ? s0 : 0;
  const int b1 = sel[2 * t + 1];
  const int nk = (b1 >= 0) ? 2 * HWc : HWc;
  const int nch = (nk + 63) >> 6;

  // Q B-frags: lane l15 = q-row within tile, 8 dims per (quad, ks)
  u16x8 qf[4][4];
#pragma unroll
  for (int qt = 0; qt < 4; ++qt) {
    int qrow = m0 + qt * 16 + l15;
    if (qrow > HWc - 1) qrow = HWc - 1;
    const u16* qp = Q + (size_t)(t * HWc + qrow) * DIMc + h * 128;
#pragma unroll
    for (int ks = 0; ks < 4; ++ks) qf[qt][ks] = *(const u16x8*)(qp + ks * 32 + quad * 8);
  }

  f32x4 oacc[2][4];
#pragma unroll
  for (int nt = 0; nt < 2; ++nt)
#pragma unroll
    for (int qt = 0; qt < 4; ++qt)
#pragma unroll
      for (int r = 0; r < 4; ++r) oacc[nt][qt][r] = 0.f;
  float lp[4] = {0.f, 0.f, 0.f, 0.f};

  const int kl_r = lane >> 4, kl_c = lane & 15;  // K staging: 4 rows x 16 chunks per instr
  const int vl_r = lane >> 3, vl_c = lane & 7;   // V staging: 8 rows x 8 chunks per instr

  for (int c = 0; c < nch; ++c) {
    const int kc = c * 64;
    // stage K chunk (16 KB, 4 glds per wave)
#pragma unroll
    for (int n = 0; n < 4; ++n) {
      int keyl = wid * 16 + n * 4 + kl_r;
      int gc = kl_c ^ (keyl & 15);
      int kg = kc + keyl;
      if (kg >= nk) kg = 0;
      int big = kg >= HWc;
      int tok = (big ? b1 : b0) * HWc + kg - (big ? HWc : 0);
      glds16(Kb + ((size_t)tok * DIMc + h * 128 + gc * 8), Ks + (wid * 16 + n * 4) * 128);
    }
    // stage V^T chunk (16 KB, 4 glds per wave); 8-token spans never straddle blocks (1560%8==0)
#pragma unroll
    for (int n = 0; n < 4; ++n) {
      int dl = wid * 32 + n * 8 + vl_r;
      int gc = vl_c ^ (dl & 7);
      int tg = kc + gc * 8;
      if (tg >= nk) tg = 0;
      int big = tg >= HWc;
      int tok = (big ? b1 : b0) * HWc + tg - (big ? HWc : 0);
      glds16(VT + ((size_t)(h * 128 + dl) * KT + tok), Vt + (wid * 32 + n * 8) * 64);
    }
    asm volatile("s_waitcnt vmcnt(0)" ::: "memory");
    __syncthreads();

    // S^T = K Q^T for this wave's 16 keys; scores already log2-scaled via qscale
    f32x4 s[4];
#pragma unroll
    for (int qt = 0; qt < 4; ++qt)
#pragma unroll
      for (int r = 0; r < 4; ++r) s[qt][r] = 0.f;
#pragma unroll
    for (int ks = 0; ks < 4; ++ks) {
      int key = wid * 16 + l15;
      u16x8 ka = *(const u16x8*)&Ks[key * 128 + (((ks * 4 + quad) ^ l15) * 8)];
#pragma unroll
      for (int qt = 0; qt < 4; ++qt) s[qt] = mfma16(ka, qf[qt][ks], s[qt]);
    }
    // one-pass softmax numerator p = 2^s (scores O(+-8): safe), mask invalid keys
    int kb_ = kc + wid * 16 + quad * 4;
#pragma unroll
    for (int qt = 0; qt < 4; ++qt) {
      u16x4 pw;
#pragma unroll
      for (int r = 0; r < 4; ++r) {
        float p = (kb_ + r < nk) ? exp2f(s[qt][r]) : 0.f;
        lp[qt] += p;
        pw[r] = f2bf(p);
      }
      *(u16x4*)&Ps[(qt * 16 + l15) * 68 + wid * 16 + quad * 4] = pw;
    }
    __syncthreads();

    // O^T += V^T P^T for this wave's 32 d rows
#pragma unroll
    for (int k2 = 0; k2 < 2; ++k2) {
      u16x8 pf[4];
#pragma unroll
      for (int qt = 0; qt < 4; ++qt)
        pf[qt] = *(const u16x8*)&Ps[(qt * 16 + l15) * 68 + k2 * 32 + quad * 8];
#pragma unroll
      for (int nt = 0; nt < 2; ++nt) {
        int d = wid * 32 + nt * 16 + l15;
        u16x8 va = *(const u16x8*)&Vt[d * 64 + (((k2 * 4 + quad) ^ (d & 7)) * 8)];
#pragma unroll
        for (int qt = 0; qt < 4; ++qt) oacc[nt][qt] = mfma16(va, pf[qt], oacc[nt][qt]);
      }
    }
    __syncthreads();
  }

  // l merge across quads then waves
#pragma unroll
  for (int qt = 0; qt < 4; ++qt) {
    float v = lp[qt];
    v += __shfl_xor(v, 16);
    v += __shfl_xor(v, 32);
    if (lane < 16) Ls[wid][qt * 16 + lane] = v;
  }
  __syncthreads();

  // epilogue: per-wave O^T staging (alias smem), then coalesced bf16 store
  float* Ot = (float*)smem + wid * 2304;  // [64 q][36]
#pragma unroll
  for (int nt = 0; nt < 2; ++nt)
#pragma unroll
    for (int qt = 0; qt < 4; ++qt)
      *(f32x4*)&Ot[(qt * 16 + l15) * 36 + nt * 16 + quad * 4] = oacc[nt][qt];
  asm volatile("s_waitcnt lgkmcnt(0)" ::: "memory");
  int qrow = m0 + lane;
  if (qrow < HWc) {
    float l = Ls[0][lane] + Ls[1][lane] + Ls[2][lane] + Ls[3][lane];
    float inv = 1.f / l;
    u16* op = O + (size_t)(t * HWc + qrow) * DIMc + h * 128 + wid * 32;
#pragma unroll
    for (int j = 0; j < 4; ++j) {
      f32x4 a = *(const f32x4*)&Ot[lane * 36 + j * 8];
      f32x4 b = *(const f32x4*)&Ot[lane * 36 + j * 8 + 4];
      u16x8 o8;
#pragma unroll
      for (int e = 0; e < 4; ++e) { o8[e] = f2bf(a[e] * inv); o8[e + 4] = f2bf(b[e] * inv); }
      *(u16x8*)(op + j * 8) = o8;
    }
  }
}

extern "C" void kernel_launch(void* const* d_in, const int* in_sizes, int n_in,
                              void* d_out, int out_size, void* d_ws, size_t ws_size,
                              hipStream_t stream) {
  const float* hs  = (const float*)d_in[0];
  const float* his = (const float*)d_in[1];
  const float* fc  = (const float*)d_in[2];
  const float* fs  = (const float*)d_in[3];
  const float* fch = (const float*)d_in[4];
  const float* fsh = (const float*)d_in[5];
  const int*   sel = (const int*)d_in[6];
  const float* Wq  = (const float*)d_in[7];
  const float* bq  = (const float*)d_in[8];
  const float* Wk  = (const float*)d_in[9];
  const float* bk  = (const float*)d_in[10];
  const float* Wv  = (const float*)d_in[11];
  const float* bv  = (const float*)d_in[12];
  const float* Wo  = (const float*)d_in[13];
  const float* bo  = (const float*)d_in[14];
  const float* gq  = (const float*)d_in[15];
  const float* gk  = (const float*)d_in[16];

  const int QT = 3120, KT = 12480, DIMc = 1536;
  u16* p = (u16*)d_ws;
  u16* hsb = p; p += (size_t)QT * DIMc;
  u16* hib = p; p += (size_t)KT * DIMc;
  u16* wqb = p; p += (size_t)DIMc * DIMc;
  u16* wkb = p; p += (size_t)DIMc * DIMc;
  u16* wvb = p; p += (size_t)DIMc * DIMc;
  u16* wob = p; p += (size_t)DIMc * DIMc;
  u16* qb  = p; p += (size_t)QT * DIMc;
  u16* kb2 = p; p += (size_t)KT * DIMc;
  u16* ab  = p; p += (size_t)QT * DIMc;   // ab before vt so GEMM A-tail overreads stay in ws
  u16* vt  = p; p += (size_t)DIMc * KT;   // V^T [1536][12480]

  cvt_bf16<<<dim3((QT * DIMc / 4 + 255) / 256), 256, 0, stream>>>(hs, hsb, QT * DIMc / 4);
  cvt_bf16<<<dim3((KT * DIMc / 4 + 255) / 256), 256, 0, stream>>>(his, hib, KT * DIMc / 4);
  cvt_w4<<<dim3(2304, 4), 256, 0, stream>>>(Wq, Wk, Wv, Wo, wqb, wkb, wvb, wob);

  gemm_v2<0><<<dim3(12, 25), 256, 0, stream>>>(hsb, wqb, bq, qb, QT, 0);
  gemm_v2<0><<<dim3(12, 98), 256, 0, stream>>>(hib, wkb, bk, kb2, KT, 0);
  gemm_v2<2><<<dim3(12, 98), 256, 0, stream>>>(hib, wvb, bv, vt, KT, KT);  // writes V^T

  const float qscale = (float)(0.08838834764831845 * 1.4426950408889634);
  norm_rope2<<<dim3(QT), 192, 0, stream>>>(qb, gq, fc, fs, qscale);
  norm_rope2<<<dim3(KT), 192, 0, stream>>>(kb2, gk, fch, fsh, 1.0f);

  attn2<<<dim3(25, 24), 256, 0, stream>>>(qb, kb2, vt, sel, ab);

  gemm_v2<1><<<dim3(12, 25), 256, 0, stream>>>(ab, wob, bo, d_out, QT, 0);
}